// Round 3
// baseline (133.146 us; speedup 1.0000x reference)
//
#include <hip/hip_runtime.h>

static constexpr int IMG = 512;
static constexpr int TX  = 64;           // tile width  (output)
static constexpr int TY  = 32;           // tile height (output)
static constexpr int LST = 72;           // LDS row stride (floats), mult of 4
static constexpr int SROWS = TY + 6;     // 38 rows staged (unified row map: r <-> y = ty0-3+r)

// g(d)*d = d * exp(-u), u = |d|/(1+d^2) in [0, 0.5] ALWAYS.
// exp(-u) via degree-5 Taylor: |err| <= 0.5^6/720 = 2.2e-5 (alternating series).
__device__ __forceinline__ float gd(float d) {
    const float t    = fmaf(d, d, 1.0f);
    const float rinv = __builtin_amdgcn_rcpf(t);
    const float u    = __builtin_fabsf(d) * rinv;
    float e = -0.008333333f;                 // -1/120
    e = fmaf(e, u,  0.041666668f);           //  1/24
    e = fmaf(e, u, -0.166666667f);           // -1/6
    e = fmaf(e, u,  0.5f);
    e = fmaf(e, u, -1.0f);
    e = fmaf(e, u,  1.0f);
    return e * d;
}

// One diffusion step, 4 pixels per thread along x.
// Column maps (per buffer): A(X0): c <-> x = tx0-4+c ; B(X1): x = tx0-2+c ; C(X2): x = tx0-1+c.
// WOFF=1 (step1): load 8 floats/row (2x b128), pixel i window = L[i+1..i+3] (parent shift +2).
// WOFF=0 (steps 2,3): load 6 floats/row (b128+b64), pixel i window = L[i..i+2] (parent shift +1).
template<int WOFF, int NR, int RLO, int NG, bool TO_GLOBAL>
__device__ __forceinline__ void diffuse_step(
    const float* __restrict__ prev, float* __restrict__ cur,
    const float* __restrict__ Wt, const float* __restrict__ bt,
    int xoff /* global x of output (c0=0,i=0) */, int ty0, int tx0,
    int tid, float* __restrict__ gout)
{
    constexpr int LOADW  = WOFF ? 8 : 6;
    constexpr int NITEMS = NR * NG;
    for (int idx = tid; idx < NITEMS; idx += 256) {
        const int rr = idx / NG;                 // constexpr divisor -> magic mul
        const int j  = idx - rr * NG;
        const int r  = RLO + rr;
        const int c0 = 4 * j;
        const float* base = prev + (r - 1) * LST + c0;   // one addr reg, const offsets

        float L0[LOADW], L1[LOADW], L2[LOADW];
        *(float4*)&L0[0] = *(const float4*)(base);
        *(float4*)&L1[0] = *(const float4*)(base + LST);
        *(float4*)&L2[0] = *(const float4*)(base + 2 * LST);
        if (WOFF) {  // 8-wide
            *(float4*)&L0[4] = *(const float4*)(base + 4);
            *(float4*)&L1[4] = *(const float4*)(base + LST + 4);
            *(float4*)&L2[4] = *(const float4*)(base + 2 * LST + 4);
        } else {     // 6-wide
            *(float2*)&L0[4] = *(const float2*)(base + 4);
            *(float2*)&L1[4] = *(const float2*)(base + LST + 4);
            *(float2*)&L2[4] = *(const float2*)(base + 2 * LST + 4);
        }

        float acc[4] = {0.f, 0.f, 0.f, 0.f};
#pragma unroll
        for (int k = 0; k < 8; ++k) {
            const float w0 = Wt[9*k+0], w1 = Wt[9*k+1], w2 = Wt[9*k+2];
            const float w3 = Wt[9*k+3], w4 = Wt[9*k+4], w5 = Wt[9*k+5];
            const float w6 = Wt[9*k+6], w7 = Wt[9*k+7], w8 = Wt[9*k+8];
            const float bk = bt[k];
#pragma unroll
            for (int i = 0; i < 4; ++i) {
                float d = bk;
                d = fmaf(w0, L0[WOFF+i],   d);
                d = fmaf(w1, L0[WOFF+i+1], d);
                d = fmaf(w2, L0[WOFF+i+2], d);
                d = fmaf(w3, L1[WOFF+i],   d);
                d = fmaf(w4, L1[WOFF+i+1], d);
                d = fmaf(w5, L1[WOFF+i+2], d);
                d = fmaf(w6, L2[WOFF+i],   d);
                d = fmaf(w7, L2[WOFF+i+1], d);
                d = fmaf(w8, L2[WOFF+i+2], d);
                acc[i] += gd(d);
            }
        }

        float4 v;
        v.x = L1[WOFF+1] - acc[0] * 0.125f;
        v.y = L1[WOFF+2] - acc[1] * 0.125f;
        v.z = L1[WOFF+3] - acc[2] * 0.125f;
        v.w = L1[WOFF+4] - acc[3] * 0.125f;

        const int gy = ty0 - 3 + r;
        if (TO_GLOBAL) {
            *(float4*)&gout[gy * IMG + tx0 + c0] = v;    // always in-image
        } else {
            const bool ry  = (unsigned)gy < (unsigned)IMG;
            const int  gx0 = xoff + c0;
            v.x = (ry && (unsigned)(gx0 + 0) < (unsigned)IMG) ? v.x : 0.f;
            v.y = (ry && (unsigned)(gx0 + 1) < (unsigned)IMG) ? v.y : 0.f;
            v.z = (ry && (unsigned)(gx0 + 2) < (unsigned)IMG) ? v.z : 0.f;
            v.w = (ry && (unsigned)(gx0 + 3) < (unsigned)IMG) ? v.w : 0.f;
            *(float4*)&cur[r * LST + c0] = v;
        }
    }
}

__global__ __launch_bounds__(256, 6) void deep_ad_kernel(
    const float* __restrict__ x, const float* __restrict__ W,
    const float* __restrict__ b, float* __restrict__ out)
{
    __shared__ float A[SROWS * LST];   // X0, later reused for X2
    __shared__ float Bs[SROWS * LST];  // X1

    const int tid = threadIdx.x;
    const int tx0 = blockIdx.x * TX;
    const int ty0 = blockIdx.y * TY;
    const float* xin  = x   + (size_t)blockIdx.z * (IMG * IMG);
    float*       gout = out + (size_t)blockIdx.z * (IMG * IMG);

    // Stage X0: 38 rows x 72 cols (x = tx0-4+4j, aligned float4), zero outside image.
    for (int idx = tid; idx < SROWS * 18; idx += 256) {
        const int r = idx / 18, j = idx - (idx / 18) * 18;
        const int gy = ty0 - 3 + r;
        const int gx = tx0 - 4 + 4 * j;
        float4 v = {0.f, 0.f, 0.f, 0.f};
        if ((unsigned)gy < (unsigned)IMG && (unsigned)gx < (unsigned)IMG)
            v = *(const float4*)(xin + gy * IMG + gx);
        *(float4*)&A[r * LST + 4 * j] = v;
    }
    __syncthreads();

    // step1: rows 1..36 (y: ty0-2..ty0+33), 17 groups (x: tx0-2..tx0+65) -> Bs
    diffuse_step<1, TY + 4, 1, 17, false>(A,  Bs, W + 0,   b + 0,  tx0 - 2, ty0, tx0, tid, nullptr);
    __syncthreads();
    // step2: rows 2..35, 17 groups (x: tx0-1..tx0+66; last 2 cols garbage, never read) -> A
    diffuse_step<0, TY + 2, 2, 17, false>(Bs, A,  W + 72,  b + 8,  tx0 - 1, ty0, tx0, tid, nullptr);
    __syncthreads();
    // step3: rows 3..34 (y: ty0..ty0+31), 16 groups (x: tx0..tx0+63) -> global
    diffuse_step<0, TY,     3, 16, true >(A, nullptr, W + 144, b + 16, 0, ty0, tx0, tid, gout);
}

extern "C" void kernel_launch(void* const* d_in, const int* in_sizes, int n_in,
                              void* d_out, int out_size, void* d_ws, size_t ws_size,
                              hipStream_t stream)
{
    const float* x = (const float*)d_in[0];
    const float* W = (const float*)d_in[1];  // [3,8,1,3,3]
    const float* b = (const float*)d_in[2];  // [3,8]
    float* out = (float*)d_out;
    const int N = in_sizes[0] / (IMG * IMG); // 16
    dim3 grid(IMG / TX, IMG / TY, N);
    deep_ad_kernel<<<grid, 256, 0, stream>>>(x, W, b, out);
}

// Round 4
// 126.731 us; speedup vs baseline: 1.0506x; 1.0506x over previous
//
#include <hip/hip_runtime.h>

static constexpr int IMG = 512;
static constexpr int TX  = 64;           // tile width  (output)
static constexpr int TY  = 16;           // tile height (output)
static constexpr int LST = 72;           // LDS row stride (floats)
static constexpr int SROWS  = TY + 6;    // 22 staged rows (r <-> y = ty0-3+r)
static constexpr int NSTAGE = SROWS * 18; // 396 float4 staging items

// One diffusion step, single-wave block, 4 px/thread, prefetch-pipelined.
// Column maps: A(X0): x = tx0-4+c ; B(X1): x = tx0-2+c ; A(X2): x = tx0-1+c.
template<int WOFF, int NR, int RLO, int NG, bool TO_GLOBAL>
__device__ __forceinline__ void diffuse_step(
    const float* __restrict__ prev, float* __restrict__ cur,
    const float* __restrict__ Wt, const float* __restrict__ bt,
    int xoff, int ty0, int tx0, int tid, float* __restrict__ gout)
{
    constexpr int LOADW  = WOFF ? 8 : 6;
    constexpr int NITEMS = NR * NG;

    float L0[LOADW], L1[LOADW], L2[LOADW];
    {   // initial load (idx = tid; clamp if tid >= NITEMS, harmless)
        const int idx0 = (tid < NITEMS) ? tid : 0;
        const int rr = idx0 / NG, j = idx0 - rr * NG;
        const float* base = prev + (RLO + rr - 1) * LST + 4 * j;
        *(float4*)&L0[0] = *(const float4*)(base);
        *(float4*)&L1[0] = *(const float4*)(base + LST);
        *(float4*)&L2[0] = *(const float4*)(base + 2 * LST);
        if (WOFF) {
            *(float4*)&L0[4] = *(const float4*)(base + 4);
            *(float4*)&L1[4] = *(const float4*)(base + LST + 4);
            *(float4*)&L2[4] = *(const float4*)(base + 2 * LST + 4);
        } else {
            *(float2*)&L0[4] = *(const float2*)(base + 4);
            *(float2*)&L1[4] = *(const float2*)(base + LST + 4);
            *(float2*)&L2[4] = *(const float2*)(base + 2 * LST + 4);
        }
    }

    for (int idx = tid; idx < NITEMS; idx += 64) {
        // ---- prefetch next item's window (issued before compute) ----
        float P0[LOADW], P1[LOADW], P2[LOADW];
        {
            const int nidx = (idx + 64 < NITEMS) ? (idx + 64) : idx;
            const int rr = nidx / NG, j = nidx - rr * NG;
            const float* base = prev + (RLO + rr - 1) * LST + 4 * j;
            *(float4*)&P0[0] = *(const float4*)(base);
            *(float4*)&P1[0] = *(const float4*)(base + LST);
            *(float4*)&P2[0] = *(const float4*)(base + 2 * LST);
            if (WOFF) {
                *(float4*)&P0[4] = *(const float4*)(base + 4);
                *(float4*)&P1[4] = *(const float4*)(base + LST + 4);
                *(float4*)&P2[4] = *(const float4*)(base + 2 * LST + 4);
            } else {
                *(float2*)&P0[4] = *(const float2*)(base + 4);
                *(float2*)&P1[4] = *(const float2*)(base + LST + 4);
                *(float2*)&P2[4] = *(const float2*)(base + 2 * LST + 4);
            }
        }

        // ---- compute current item ----
        const int rr = idx / NG, j = idx - rr * NG;
        const int r  = RLO + rr, c0 = 4 * j;

        float acc[4] = {0.f, 0.f, 0.f, 0.f};
#pragma unroll
        for (int k = 0; k < 8; ++k) {
            const float w0 = Wt[9*k+0], w1 = Wt[9*k+1], w2 = Wt[9*k+2];
            const float w3 = Wt[9*k+3], w4 = Wt[9*k+4], w5 = Wt[9*k+5];
            const float w6 = Wt[9*k+6], w7 = Wt[9*k+7], w8 = Wt[9*k+8];
            const float bk = bt[k];
#pragma unroll
            for (int i = 0; i < 4; ++i) {
                float d = bk;
                d = fmaf(w0, L0[WOFF+i],   d);
                d = fmaf(w1, L0[WOFF+i+1], d);
                d = fmaf(w2, L0[WOFF+i+2], d);
                d = fmaf(w3, L1[WOFF+i],   d);
                d = fmaf(w4, L1[WOFF+i+1], d);
                d = fmaf(w5, L1[WOFF+i+2], d);
                d = fmaf(w6, L2[WOFF+i],   d);
                d = fmaf(w7, L2[WOFF+i+1], d);
                d = fmaf(w8, L2[WOFF+i+2], d);
                const float t    = fmaf(d, d, 1.0f);
                const float rinv = __builtin_amdgcn_rcpf(t);
                const float e    = __builtin_amdgcn_exp2f(
                                       -1.442695040888963f * __builtin_fabsf(d) * rinv);
                acc[i] = fmaf(e, d, acc[i]);
            }
        }

        float4 v;
        v.x = L1[WOFF+1] - acc[0] * 0.125f;
        v.y = L1[WOFF+2] - acc[1] * 0.125f;
        v.z = L1[WOFF+3] - acc[2] * 0.125f;
        v.w = L1[WOFF+4] - acc[3] * 0.125f;

        const int gy = ty0 - 3 + r;
        if (TO_GLOBAL) {
            *(float4*)&gout[gy * IMG + tx0 + c0] = v;
        } else {
            const bool ry  = (unsigned)gy < (unsigned)IMG;
            const int  gx0 = xoff + c0;
            v.x = (ry && (unsigned)(gx0 + 0) < (unsigned)IMG) ? v.x : 0.f;
            v.y = (ry && (unsigned)(gx0 + 1) < (unsigned)IMG) ? v.y : 0.f;
            v.z = (ry && (unsigned)(gx0 + 2) < (unsigned)IMG) ? v.z : 0.f;
            v.w = (ry && (unsigned)(gx0 + 3) < (unsigned)IMG) ? v.w : 0.f;
            *(float4*)&cur[r * LST + c0] = v;
        }

        // rotate prefetched window in (regs, elided by renaming/unroll)
#pragma unroll
        for (int q = 0; q < LOADW; ++q) { L0[q] = P0[q]; L1[q] = P1[q]; L2[q] = P2[q]; }
    }
}

__global__ __launch_bounds__(64) void deep_ad_kernel(
    const float* __restrict__ x, const float* __restrict__ W,
    const float* __restrict__ b, float* __restrict__ out)
{
    __shared__ float A[SROWS * LST];   // X0, later reused for X2
    __shared__ float Bs[SROWS * LST];  // X1

    const int tid = threadIdx.x;
    const int tx0 = blockIdx.x * TX;
    const int ty0 = blockIdx.y * TY;
    const float* xin  = x   + (size_t)blockIdx.z * (IMG * IMG);
    float*       gout = out + (size_t)blockIdx.z * (IMG * IMG);

    // Stage X0 (22 rows x 72 cols): issue all loads first, one wait, then LDS writes.
    {
        float4 sv[7];
#pragma unroll
        for (int q = 0; q < 7; ++q) {
            const int item = tid + 64 * q;
            const int rr = item / 18, j = item - rr * 18;
            const int gy = ty0 - 3 + rr;
            const int gx = tx0 - 4 + 4 * j;
            float4 v = {0.f, 0.f, 0.f, 0.f};
            if (item < NSTAGE && (unsigned)gy < (unsigned)IMG && (unsigned)gx < (unsigned)IMG)
                v = *(const float4*)(xin + gy * IMG + gx);
            sv[q] = v;
        }
#pragma unroll
        for (int q = 0; q < 7; ++q) {
            const int item = tid + 64 * q;
            if (item < NSTAGE) *(float4*)&A[item * 4] = sv[q];
        }
    }
    __syncthreads();   // single-wave block: no cross-wave phase-locking

    // step1: rows r=1..20 (y: ty0-2..ty0+17), 17 groups (x: tx0-2..tx0+65) -> Bs
    diffuse_step<1, TY + 4, 1, 17, false>(A,  Bs, W + 0,   b + 0,  tx0 - 2, ty0, tx0, tid, nullptr);
    __syncthreads();
    // step2: rows r=2..19, 17 groups (x: tx0-1..tx0+66; last 2 cols garbage, never read) -> A
    diffuse_step<0, TY + 2, 2, 17, false>(Bs, A,  W + 72,  b + 8,  tx0 - 1, ty0, tx0, tid, nullptr);
    __syncthreads();
    // step3: rows r=3..18 (y: ty0..ty0+15), 16 groups (x: tx0..tx0+63) -> global
    diffuse_step<0, TY,     3, 16, true >(A, nullptr, W + 144, b + 16, 0, ty0, tx0, tid, gout);
}

extern "C" void kernel_launch(void* const* d_in, const int* in_sizes, int n_in,
                              void* d_out, int out_size, void* d_ws, size_t ws_size,
                              hipStream_t stream)
{
    const float* x = (const float*)d_in[0];
    const float* W = (const float*)d_in[1];  // [3,8,1,3,3]
    const float* b = (const float*)d_in[2];  // [3,8]
    float* out = (float*)d_out;
    const int N = in_sizes[0] / (IMG * IMG); // 16
    dim3 grid(IMG / TX, IMG / TY, N);
    deep_ad_kernel<<<grid, 64, 0, stream>>>(x, W, b, out);
}